// Round 1
// baseline (1684.126 us; speedup 1.0000x reference)
//
#include <hip/hip_runtime.h>

// Problem constants (from reference)
#define NN 50000
#define EE 1600000
#define FF 128
#define HH 64
#define CC 40
#define KK 4

// ---------- setup kernels ----------

// deg = segment_sum(w over src) ; cnt = in-degree histogram over dst (for CSR)
__global__ void deg_cnt_kernel(const int* __restrict__ src, const int* __restrict__ dst,
                               const float* __restrict__ w, float* __restrict__ deg,
                               int* __restrict__ cnt, int E) {
    int e = blockIdx.x * blockDim.x + threadIdx.x;
    if (e >= E) return;
    atomicAdd(&deg[src[e]], w[e]);
    atomicAdd(&cnt[dst[e]], 1);
}

// dis = deg>0 ? rsqrt(max(deg,1e-12)) : 0 ; diag = deg>0 ? 0 : -1
__global__ void norm_kernel(const float* __restrict__ deg, float* __restrict__ dis,
                            float* __restrict__ diag, int N) {
    int n = blockIdx.x * blockDim.x + threadIdx.x;
    if (n >= N) return;
    float d = deg[n];
    dis[n]  = (d > 0.f) ? rsqrtf(fmaxf(d, 1e-12f)) : 0.f;
    diag[n] = (d > 0.f) ? 0.f : -1.f;
}

// exclusive prefix scan of cnt[N] -> row_start[N+1]; single block of 1024
__global__ void scan_kernel(const int* __restrict__ cnt, int* __restrict__ row_start, int N) {
    __shared__ int buf[1024];
    __shared__ int carry_s;
    int t = threadIdx.x;
    if (t == 0) carry_s = 0;
    __syncthreads();
    for (int base = 0; base < N; base += 1024) {
        int v = (base + t < N) ? cnt[base + t] : 0;
        buf[t] = v;
        __syncthreads();
        // Hillis-Steele inclusive scan
        for (int off = 1; off < 1024; off <<= 1) {
            int x = (t >= off) ? buf[t - off] : 0;
            __syncthreads();
            buf[t] += x;
            __syncthreads();
        }
        int incl = buf[t];
        int carry = carry_s;
        if (base + t < N) row_start[base + t] = carry + incl - v;  // exclusive
        __syncthreads();
        if (t == 1023) carry_s = carry + buf[1023];
        __syncthreads();
    }
    if (t == 0) row_start[N] = carry_s;
}

// fill CSR grouped by dst; compute w_norm inline: -dis[src]*w*dis[dst]
__global__ void fill_csr_kernel(const int* __restrict__ src, const int* __restrict__ dst,
                                const float* __restrict__ w, const float* __restrict__ dis,
                                const int* __restrict__ row_start, int* __restrict__ cursor,
                                int* __restrict__ csr_src, float* __restrict__ csr_w, int E) {
    int e = blockIdx.x * blockDim.x + threadIdx.x;
    if (e >= E) return;
    int s = src[e], d = dst[e];
    int pos = row_start[d] + atomicAdd(&cursor[d], 1);
    csr_src[pos] = s;
    csr_w[pos] = -dis[s] * w[e] * dis[d];
}

// ---------- propagation: out = alpha*(diag*h + sum_{in-edges} w*h[src]) + beta*prev ----------
// one block per node, blockDim == F (lane = feature)
template <int F>
__global__ void prop_kernel(const float* __restrict__ h, const float* __restrict__ prev,
                            const float* __restrict__ diag, const int* __restrict__ row_start,
                            const int* __restrict__ csr_src, const float* __restrict__ csr_w,
                            float* __restrict__ out, float alpha, float beta) {
    int n = blockIdx.x;
    int f = threadIdx.x;
    size_t nf = (size_t)n * F + f;
    float acc = diag[n] * h[nf];
    int j0 = row_start[n], j1 = row_start[n + 1];
    for (int j = j0; j < j1; ++j) {
        int s = csr_src[j];
        float w = csr_w[j];
        acc = fmaf(w, h[(size_t)s * F + f], acc);
    }
    float r = alpha * acc;
    if (beta != 0.f) r = fmaf(beta, prev[nf], r);
    out[nf] = r;
}

// ---------- incremental GEMM: Z[n,j] (+)= sum_f T[n,f] * Wk[f*Hout+j]  (+ bias on init) ----------
__global__ void gemm_accum_kernel(const float* __restrict__ T, const float* __restrict__ Wk,
                                  const float* __restrict__ bias, float* __restrict__ Z,
                                  int N, int Fin, int Hout, int init) {
    int tid = blockIdx.x * blockDim.x + threadIdx.x;
    if (tid >= N * Hout) return;
    int n = tid / Hout;
    int j = tid - n * Hout;
    const float* trow = T + (size_t)n * Fin;
    float acc = init ? bias[j] : Z[tid];
    #pragma unroll 8
    for (int f = 0; f < Fin; ++f)
        acc = fmaf(trow[f], Wk[f * Hout + j], acc);
    Z[tid] = acc;
}

__global__ void relu_kernel(float* __restrict__ x, int n) {
    int i = blockIdx.x * blockDim.x + threadIdx.x;
    if (i < n) x[i] = fmaxf(x[i], 0.f);
}

// ---------- launcher ----------
extern "C" void kernel_launch(void* const* d_in, const int* in_sizes, int n_in,
                              void* d_out, int out_size, void* d_ws, size_t ws_size,
                              hipStream_t stream) {
    const float* x    = (const float*)d_in[0];         // [N, F]
    const int*   eidx = (const int*)d_in[1];           // [2, E]
    const float* ew   = (const float*)d_in[2];         // [E]
    const float* W1   = (const float*)d_in[3];         // [K*F, H]
    const float* b1   = (const float*)d_in[4];         // [H]
    const float* W2   = (const float*)d_in[5];         // [K*H, C]
    const float* b2   = (const float*)d_in[6];         // [C]
    float* out = (float*)d_out;                        // [N, C]

    const int* src = eidx;        // edge_index[0]
    const int* dst = eidx + EE;   // edge_index[1]

    // workspace carve-up (floats then ints)
    float* p = (float*)d_ws;
    float* deg    = p;             p += NN;
    float* dis    = p;             p += NN;
    float* diag   = p;             p += NN;
    float* csr_w  = p;             p += EE;
    float* T1     = p;             p += (size_t)NN * FF;
    float* T2     = p;             p += (size_t)NN * FF;
    float* T3     = p;             p += (size_t)NN * FF;
    float* Zacc   = p;             p += (size_t)NN * HH;   // layer-1 pre-activation -> h
    int* cnt       = (int*)p;
    int* row_start = cnt + NN;
    int* cursor    = row_start + NN + 1;
    int* csr_src   = cursor + NN;

    // zero accumulators
    hipMemsetAsync(deg,    0, NN * sizeof(float), stream);
    hipMemsetAsync(cnt,    0, NN * sizeof(int),   stream);
    hipMemsetAsync(cursor, 0, NN * sizeof(int),   stream);

    const int B = 256;
    deg_cnt_kernel<<<(EE + B - 1) / B, B, 0, stream>>>(src, dst, ew, deg, cnt, EE);
    norm_kernel<<<(NN + B - 1) / B, B, 0, stream>>>(deg, dis, diag, NN);
    scan_kernel<<<1, 1024, 0, stream>>>(cnt, row_start, NN);
    fill_csr_kernel<<<(EE + B - 1) / B, B, 0, stream>>>(src, dst, ew, dis, row_start, cursor,
                                                        csr_src, csr_w, EE);

    // ---------------- layer 1 (Fin=128, Hout=64) ----------------
    int g1 = (NN * HH + B - 1) / B;
    // k=0: T0 = x
    gemm_accum_kernel<<<g1, B, 0, stream>>>(x, W1 + 0 * FF * HH, b1, Zacc, NN, FF, HH, 1);
    // k=1: T1 = L̂ x
    prop_kernel<FF><<<NN, FF, 0, stream>>>(x, x, diag, row_start, csr_src, csr_w, T1, 1.f, 0.f);
    gemm_accum_kernel<<<g1, B, 0, stream>>>(T1, W1 + 1 * FF * HH, b1, Zacc, NN, FF, HH, 0);
    // k=2: T2 = 2 L̂ T1 - x
    prop_kernel<FF><<<NN, FF, 0, stream>>>(T1, x, diag, row_start, csr_src, csr_w, T2, 2.f, -1.f);
    gemm_accum_kernel<<<g1, B, 0, stream>>>(T2, W1 + 2 * FF * HH, b1, Zacc, NN, FF, HH, 0);
    // k=3: T3 = 2 L̂ T2 - T1
    prop_kernel<FF><<<NN, FF, 0, stream>>>(T2, T1, diag, row_start, csr_src, csr_w, T3, 2.f, -1.f);
    gemm_accum_kernel<<<g1, B, 0, stream>>>(T3, W1 + 3 * FF * HH, b1, Zacc, NN, FF, HH, 0);
    // ReLU in place -> h
    relu_kernel<<<(NN * HH + B - 1) / B, B, 0, stream>>>(Zacc, NN * HH);
    float* h = Zacc;

    // ---------------- layer 2 (Fin=64, Hout=40), reuse T buffers as S ----------------
    float* S1 = T1; float* S2 = T2; float* S3 = T3;
    int g2 = (NN * CC + B - 1) / B;
    gemm_accum_kernel<<<g2, B, 0, stream>>>(h, W2 + 0 * HH * CC, b2, out, NN, HH, CC, 1);
    prop_kernel<HH><<<NN, HH, 0, stream>>>(h, h, diag, row_start, csr_src, csr_w, S1, 1.f, 0.f);
    gemm_accum_kernel<<<g2, B, 0, stream>>>(S1, W2 + 1 * HH * CC, b2, out, NN, HH, CC, 0);
    prop_kernel<HH><<<NN, HH, 0, stream>>>(S1, h, diag, row_start, csr_src, csr_w, S2, 2.f, -1.f);
    gemm_accum_kernel<<<g2, B, 0, stream>>>(S2, W2 + 2 * HH * CC, b2, out, NN, HH, CC, 0);
    prop_kernel<HH><<<NN, HH, 0, stream>>>(S2, S1, diag, row_start, csr_src, csr_w, S3, 2.f, -1.f);
    gemm_accum_kernel<<<g2, B, 0, stream>>>(S3, W2 + 3 * HH * CC, b2, out, NN, HH, CC, 0);
}

// Round 2
// 1485.011 us; speedup vs baseline: 1.1341x; 1.1341x over previous
//
#include <hip/hip_runtime.h>

// Problem constants (from reference)
#define NN 50000
#define EE 1600000
#define FF 128
#define HH 64
#define CC 40
#define KK 4

// ---------- setup kernels ----------

__global__ void deg_cnt_kernel(const int* __restrict__ src, const int* __restrict__ dst,
                               const float* __restrict__ w, float* __restrict__ deg,
                               int* __restrict__ cnt, int E) {
    int e = blockIdx.x * blockDim.x + threadIdx.x;
    if (e >= E) return;
    atomicAdd(&deg[src[e]], w[e]);
    atomicAdd(&cnt[dst[e]], 1);
}

__global__ void norm_kernel(const float* __restrict__ deg, float* __restrict__ dis,
                            float* __restrict__ diag, int N) {
    int n = blockIdx.x * blockDim.x + threadIdx.x;
    if (n >= N) return;
    float d = deg[n];
    dis[n]  = (d > 0.f) ? rsqrtf(fmaxf(d, 1e-12f)) : 0.f;
    diag[n] = (d > 0.f) ? 0.f : -1.f;
}

// exclusive prefix scan of cnt[N] -> row_start[N+1]; single block of 1024
__global__ void scan_kernel(const int* __restrict__ cnt, int* __restrict__ row_start, int N) {
    __shared__ int buf[1024];
    __shared__ int carry_s;
    int t = threadIdx.x;
    if (t == 0) carry_s = 0;
    __syncthreads();
    for (int base = 0; base < N; base += 1024) {
        int v = (base + t < N) ? cnt[base + t] : 0;
        buf[t] = v;
        __syncthreads();
        for (int off = 1; off < 1024; off <<= 1) {
            int x = (t >= off) ? buf[t - off] : 0;
            __syncthreads();
            buf[t] += x;
            __syncthreads();
        }
        int incl = buf[t];
        int carry = carry_s;
        if (base + t < N) row_start[base + t] = carry + incl - v;  // exclusive
        __syncthreads();
        if (t == 1023) carry_s = carry + buf[1023];
        __syncthreads();
    }
    if (t == 0) row_start[N] = carry_s;
}

__global__ void fill_csr_kernel(const int* __restrict__ src, const int* __restrict__ dst,
                                const float* __restrict__ w, const float* __restrict__ dis,
                                const int* __restrict__ row_start, int* __restrict__ cursor,
                                int* __restrict__ csr_src, float* __restrict__ csr_w, int E) {
    int e = blockIdx.x * blockDim.x + threadIdx.x;
    if (e >= E) return;
    int s = src[e], d = dst[e];
    int pos = row_start[d] + atomicAdd(&cursor[d], 1);
    csr_src[pos] = s;
    csr_w[pos] = -dis[s] * w[e] * dis[d];
}

// ---------- propagation: out = alpha*(diag*h + sum_in w*h[src]) + beta*prev ----------
// one block per node, blockDim == F (lane = feature).
// Edge loop unrolled x8: batched (block-uniform -> scalar) csr loads, then 8
// independent gathers in flight per thread to hide L2/LLC latency.
template <int F>
__global__ void prop_kernel(const float* __restrict__ h, const float* __restrict__ prev,
                            const float* __restrict__ diag, const int* __restrict__ row_start,
                            const int* __restrict__ csr_src, const float* __restrict__ csr_w,
                            float* __restrict__ out, float alpha, float beta) {
    int n = blockIdx.x;
    int f = threadIdx.x;
    size_t nf = (size_t)n * F + f;
    float acc = diag[n] * h[nf];
    int j0 = row_start[n], j1 = row_start[n + 1];
    int j = j0;
    for (; j + 8 <= j1; j += 8) {
        int   s[8];
        float w[8];
        #pragma unroll
        for (int u = 0; u < 8; ++u) { s[u] = csr_src[j + u]; w[u] = csr_w[j + u]; }
        float v[8];
        #pragma unroll
        for (int u = 0; u < 8; ++u) v[u] = h[(size_t)s[u] * F + f];
        #pragma unroll
        for (int u = 0; u < 8; ++u) acc = fmaf(w[u], v[u], acc);
    }
    for (; j < j1; ++j)
        acc = fmaf(csr_w[j], h[(size_t)csr_src[j] * F + f], acc);
    float r = alpha * acc;
    if (beta != 0.f) r = fmaf(beta, prev[nf], r);
    out[nf] = r;
}

// ---------- incremental GEMM: Z[n,j] (+)= sum_f T[n,f] * Wk[f*Hout+j] ----------
__global__ void gemm_accum_kernel(const float* __restrict__ T, const float* __restrict__ Wk,
                                  const float* __restrict__ bias, float* __restrict__ Z,
                                  int N, int Fin, int Hout, int init) {
    int tid = blockIdx.x * blockDim.x + threadIdx.x;
    if (tid >= N * Hout) return;
    int n = tid / Hout;
    int j = tid - n * Hout;
    const float* trow = T + (size_t)n * Fin;
    float acc = init ? bias[j] : Z[tid];
    #pragma unroll 8
    for (int f = 0; f < Fin; ++f)
        acc = fmaf(trow[f], Wk[f * Hout + j], acc);
    Z[tid] = acc;
}

__global__ void relu_kernel(float* __restrict__ x, int n) {
    int i = blockIdx.x * blockDim.x + threadIdx.x;
    if (i < n) x[i] = fmaxf(x[i], 0.f);
}

// ---------- launcher ----------
extern "C" void kernel_launch(void* const* d_in, const int* in_sizes, int n_in,
                              void* d_out, int out_size, void* d_ws, size_t ws_size,
                              hipStream_t stream) {
    const float* x    = (const float*)d_in[0];         // [N, F]
    const int*   eidx = (const int*)d_in[1];           // [2, E]
    const float* ew   = (const float*)d_in[2];         // [E]
    const float* W1   = (const float*)d_in[3];         // [K*F, H]
    const float* b1   = (const float*)d_in[4];         // [H]
    const float* W2   = (const float*)d_in[5];         // [K*H, C]
    const float* b2   = (const float*)d_in[6];         // [C]
    float* out = (float*)d_out;                        // [N, C]

    const int* src = eidx;        // edge_index[0]
    const int* dst = eidx + EE;   // edge_index[1]

    // workspace carve-up (floats then ints)
    float* p = (float*)d_ws;
    float* deg    = p;             p += NN;
    float* dis    = p;             p += NN;
    float* diag   = p;             p += NN;
    float* csr_w  = p;             p += EE;
    float* T1     = p;             p += (size_t)NN * FF;
    float* T2     = p;             p += (size_t)NN * FF;
    float* T3     = p;             p += (size_t)NN * FF;
    float* Zacc   = p;             p += (size_t)NN * HH;   // layer-1 pre-activation -> h
    int* cnt       = (int*)p;
    int* row_start = cnt + NN;
    int* cursor    = row_start + NN + 1;
    int* csr_src   = cursor + NN;

    hipMemsetAsync(deg,    0, NN * sizeof(float), stream);
    hipMemsetAsync(cnt,    0, NN * sizeof(int),   stream);
    hipMemsetAsync(cursor, 0, NN * sizeof(int),   stream);

    const int B = 256;
    deg_cnt_kernel<<<(EE + B - 1) / B, B, 0, stream>>>(src, dst, ew, deg, cnt, EE);
    norm_kernel<<<(NN + B - 1) / B, B, 0, stream>>>(deg, dis, diag, NN);
    scan_kernel<<<1, 1024, 0, stream>>>(cnt, row_start, NN);
    fill_csr_kernel<<<(EE + B - 1) / B, B, 0, stream>>>(src, dst, ew, dis, row_start, cursor,
                                                        csr_src, csr_w, EE);

    // ---------------- layer 1 (Fin=128, Hout=64) ----------------
    int g1 = (NN * HH + B - 1) / B;
    gemm_accum_kernel<<<g1, B, 0, stream>>>(x, W1 + 0 * FF * HH, b1, Zacc, NN, FF, HH, 1);
    prop_kernel<FF><<<NN, FF, 0, stream>>>(x, x, diag, row_start, csr_src, csr_w, T1, 1.f, 0.f);
    gemm_accum_kernel<<<g1, B, 0, stream>>>(T1, W1 + 1 * FF * HH, b1, Zacc, NN, FF, HH, 0);
    prop_kernel<FF><<<NN, FF, 0, stream>>>(T1, x, diag, row_start, csr_src, csr_w, T2, 2.f, -1.f);
    gemm_accum_kernel<<<g1, B, 0, stream>>>(T2, W1 + 2 * FF * HH, b1, Zacc, NN, FF, HH, 0);
    prop_kernel<FF><<<NN, FF, 0, stream>>>(T2, T1, diag, row_start, csr_src, csr_w, T3, 2.f, -1.f);
    gemm_accum_kernel<<<g1, B, 0, stream>>>(T3, W1 + 3 * FF * HH, b1, Zacc, NN, FF, HH, 0);
    relu_kernel<<<(NN * HH + B - 1) / B, B, 0, stream>>>(Zacc, NN * HH);
    float* h = Zacc;

    // ---------------- layer 2 (Fin=64, Hout=40), reuse T buffers as S ----------------
    float* S1 = T1; float* S2 = T2; float* S3 = T3;
    int g2 = (NN * CC + B - 1) / B;
    gemm_accum_kernel<<<g2, B, 0, stream>>>(h, W2 + 0 * HH * CC, b2, out, NN, HH, CC, 1);
    prop_kernel<HH><<<NN, HH, 0, stream>>>(h, h, diag, row_start, csr_src, csr_w, S1, 1.f, 0.f);
    gemm_accum_kernel<<<g2, B, 0, stream>>>(S1, W2 + 1 * HH * CC, b2, out, NN, HH, CC, 0);
    prop_kernel<HH><<<NN, HH, 0, stream>>>(S1, h, diag, row_start, csr_src, csr_w, S2, 2.f, -1.f);
    gemm_accum_kernel<<<g2, B, 0, stream>>>(S2, W2 + 2 * HH * CC, b2, out, NN, HH, CC, 0);
    prop_kernel<HH><<<NN, HH, 0, stream>>>(S2, S1, diag, row_start, csr_src, csr_w, S3, 2.f, -1.f);
    gemm_accum_kernel<<<g2, B, 0, stream>>>(S3, W2 + 3 * HH * CC, b2, out, NN, HH, CC, 0);
}

// Round 3
// 1171.717 us; speedup vs baseline: 1.4373x; 1.2674x over previous
//
#include <hip/hip_runtime.h>

// Problem constants (from reference)
#define NN 50000
#define EE 1600000
#define FF 128
#define HH 64
#define CC 40
#define KK 4

// Setup partitioning: 32 edge-chunks x 8 node-slices = 256 blocks, LDS histograms
#define NCHUNK 32
#define NSLICE 8
#define CHUNK_E (EE / NCHUNK)   // 50000
#define SLICE_N (NN / NSLICE)   // 6250
#define NB 196                  // ceil(NN/256) scan blocks

// ---------- setup: LDS-privatized histograms (zero global atomics) ----------
// block = (slice s, chunk c); builds deg (sum w over src) and cnt (count over dst)
// partials for node range [s*SLICE_N, (s+1)*SLICE_N) over edge range of chunk c.
__global__ __launch_bounds__(1024) void partial_hist_kernel(
    const int* __restrict__ src, const int* __restrict__ dst,
    const float* __restrict__ w,
    float* __restrict__ pdeg, int* __restrict__ pcnt) {
    __shared__ float ldeg[SLICE_N];
    __shared__ int   lcnt[SLICE_N];
    int s = blockIdx.x % NSLICE;
    int c = blockIdx.x / NSLICE;
    int base = s * SLICE_N;
    for (int i = threadIdx.x; i < SLICE_N; i += 1024) { ldeg[i] = 0.f; lcnt[i] = 0; }
    __syncthreads();
    int e0 = c * CHUNK_E;
    for (int e = e0 + threadIdx.x; e < e0 + CHUNK_E; e += 1024) {
        int se = src[e], de = dst[e];
        unsigned us = (unsigned)(se - base), ud = (unsigned)(de - base);
        if (us < SLICE_N) atomicAdd(&ldeg[us], w[e]);
        if (ud < SLICE_N) atomicAdd(&lcnt[ud], 1);
    }
    __syncthreads();
    for (int i = threadIdx.x; i < SLICE_N; i += 1024) {
        pdeg[(size_t)c * NN + base + i] = ldeg[i];
        pcnt[(size_t)c * NN + base + i] = lcnt[i];
    }
}

// per node: deg = sum_c pdeg; pcnt[c][n] -> chunk-exclusive offsets (in place);
// cnt[n] = total; dis/diag from deg.
__global__ void reduce_kernel(const float* __restrict__ pdeg, int* __restrict__ pcnt,
                              int* __restrict__ cnt, float* __restrict__ dis,
                              float* __restrict__ diag) {
    int n = blockIdx.x * blockDim.x + threadIdx.x;
    if (n >= NN) return;
    float dsum = 0.f;
    #pragma unroll
    for (int c = 0; c < NCHUNK; ++c) dsum += pdeg[(size_t)c * NN + n];
    int run = 0;
    #pragma unroll
    for (int c = 0; c < NCHUNK; ++c) {
        int t = pcnt[(size_t)c * NN + n];
        pcnt[(size_t)c * NN + n] = run;
        run += t;
    }
    cnt[n] = run;
    dis[n]  = (dsum > 0.f) ? rsqrtf(fmaxf(dsum, 1e-12f)) : 0.f;
    diag[n] = (dsum > 0.f) ? 0.f : -1.f;
}

// ---------- 3-kernel exclusive scan of cnt[NN] -> row_start[NN+1] ----------
__global__ void scanA_kernel(const int* __restrict__ cnt, int* __restrict__ bsum) {
    __shared__ int sh[256];
    int i = blockIdx.x * 256 + threadIdx.x;
    sh[threadIdx.x] = (i < NN) ? cnt[i] : 0;
    __syncthreads();
    for (int off = 128; off > 0; off >>= 1) {
        if (threadIdx.x < off) sh[threadIdx.x] += sh[threadIdx.x + off];
        __syncthreads();
    }
    if (threadIdx.x == 0) bsum[blockIdx.x] = sh[0];
}

__global__ void scanB_kernel(const int* __restrict__ bsum, int* __restrict__ boff,
                             int* __restrict__ row_start) {
    if (threadIdx.x == 0) {
        int run = 0;
        for (int b = 0; b < NB; ++b) { boff[b] = run; run += bsum[b]; }
        row_start[NN] = run;
    }
}

__global__ void scanC_kernel(const int* __restrict__ cnt, const int* __restrict__ boff,
                             int* __restrict__ row_start) {
    __shared__ int sh[256];
    int t = threadIdx.x;
    int i = blockIdx.x * 256 + t;
    int v = (i < NN) ? cnt[i] : 0;
    sh[t] = v;
    __syncthreads();
    for (int off = 1; off < 256; off <<= 1) {
        int x = (t >= off) ? sh[t - off] : 0;
        __syncthreads();
        sh[t] += x;
        __syncthreads();
    }
    if (i < NN) row_start[i] = boff[blockIdx.x] + sh[t] - v;
}

// ---------- CSR fill with LDS cursors (zero global atomics) ----------
__global__ __launch_bounds__(1024) void fill_kernel(
    const int* __restrict__ src, const int* __restrict__ dst,
    const float* __restrict__ w, const float* __restrict__ dis,
    const int* __restrict__ row_start, const int* __restrict__ pcnt,
    int* __restrict__ csr_src, float* __restrict__ csr_w) {
    __shared__ int lcur[SLICE_N];
    int s = blockIdx.x % NSLICE;
    int c = blockIdx.x / NSLICE;
    int base = s * SLICE_N;
    for (int i = threadIdx.x; i < SLICE_N; i += 1024) lcur[i] = 0;
    __syncthreads();
    int e0 = c * CHUNK_E;
    for (int e = e0 + threadIdx.x; e < e0 + CHUNK_E; e += 1024) {
        int de = dst[e];
        unsigned ud = (unsigned)(de - base);
        if (ud < SLICE_N) {
            int se = src[e];
            int off = atomicAdd(&lcur[ud], 1);
            int pos = row_start[de] + pcnt[(size_t)c * NN + de] + off;
            csr_src[pos] = se;
            csr_w[pos] = -dis[se] * w[e] * dis[de];
        }
    }
}

// ---------- propagation: out = alpha*(diag*h + sum_in w*h[src]) + beta*prev ----------
// one block per node, blockDim == F (lane = feature); edge loop unrolled x8 for MLP.
template <int F>
__global__ void prop_kernel(const float* __restrict__ h, const float* __restrict__ prev,
                            const float* __restrict__ diag, const int* __restrict__ row_start,
                            const int* __restrict__ csr_src, const float* __restrict__ csr_w,
                            float* __restrict__ out, float alpha, float beta) {
    int n = blockIdx.x;
    int f = threadIdx.x;
    size_t nf = (size_t)n * F + f;
    float acc = diag[n] * h[nf];
    int j0 = row_start[n], j1 = row_start[n + 1];
    int j = j0;
    for (; j + 8 <= j1; j += 8) {
        int   s[8];
        float w[8];
        #pragma unroll
        for (int u = 0; u < 8; ++u) { s[u] = csr_src[j + u]; w[u] = csr_w[j + u]; }
        float v[8];
        #pragma unroll
        for (int u = 0; u < 8; ++u) v[u] = h[(size_t)s[u] * F + f];
        #pragma unroll
        for (int u = 0; u < 8; ++u) acc = fmaf(w[u], v[u], acc);
    }
    for (; j < j1; ++j)
        acc = fmaf(csr_w[j], h[(size_t)csr_src[j] * F + f], acc);
    float r = alpha * acc;
    if (beta != 0.f) r = fmaf(beta, prev[nf], r);
    out[nf] = r;
}

// ---------- incremental GEMM: Z[n,j] (+)= sum_f T[n,f] * Wk[f*Hout+j] ----------
__global__ void gemm_accum_kernel(const float* __restrict__ T, const float* __restrict__ Wk,
                                  const float* __restrict__ bias, float* __restrict__ Z,
                                  int N, int Fin, int Hout, int init) {
    int tid = blockIdx.x * blockDim.x + threadIdx.x;
    if (tid >= N * Hout) return;
    int n = tid / Hout;
    int j = tid - n * Hout;
    const float* trow = T + (size_t)n * Fin;
    float acc = init ? bias[j] : Z[tid];
    #pragma unroll 8
    for (int f = 0; f < Fin; ++f)
        acc = fmaf(trow[f], Wk[f * Hout + j], acc);
    Z[tid] = acc;
}

__global__ void relu_kernel(float* __restrict__ x, int n) {
    int i = blockIdx.x * blockDim.x + threadIdx.x;
    if (i < n) x[i] = fmaxf(x[i], 0.f);
}

// ---------- launcher ----------
extern "C" void kernel_launch(void* const* d_in, const int* in_sizes, int n_in,
                              void* d_out, int out_size, void* d_ws, size_t ws_size,
                              hipStream_t stream) {
    const float* x    = (const float*)d_in[0];         // [N, F]
    const int*   eidx = (const int*)d_in[1];           // [2, E]
    const float* ew   = (const float*)d_in[2];         // [E]
    const float* W1   = (const float*)d_in[3];         // [K*F, H]
    const float* b1   = (const float*)d_in[4];         // [H]
    const float* W2   = (const float*)d_in[5];         // [K*H, C]
    const float* b2   = (const float*)d_in[6];         // [C]
    float* out = (float*)d_out;                        // [N, C]

    const int* src = eidx;        // edge_index[0]
    const int* dst = eidx + EE;   // edge_index[1]

    // workspace carve-up (floats then ints)
    float* p = (float*)d_ws;
    float* dis    = p;             p += NN;
    float* diag   = p;             p += NN;
    float* csr_w  = p;             p += EE;
    float* T1     = p;             p += (size_t)NN * FF;
    float* T2     = p;             p += (size_t)NN * FF;
    float* T3     = p;             p += (size_t)NN * FF;
    float* Zacc   = p;             p += (size_t)NN * HH;   // layer-1 pre-activation -> h
    int* cnt       = (int*)p;
    int* row_start = cnt + NN;          // NN+1
    int* csr_src   = row_start + NN + 1;
    int* bsum      = csr_src + EE;      // NB
    int* boff      = bsum + NB;         // NB

    // Partials alias T2/T3: dead before the props that write T2/T3 run
    // (stream order: partial_hist -> reduce -> scan -> fill -> props).
    float* pdeg = T2;            // NCHUNK*NN floats = 6.4 MB (T2 is 25.6 MB)
    int*   pcnt = (int*)T3;      // NCHUNK*NN ints

    const int B = 256;
    partial_hist_kernel<<<NCHUNK * NSLICE, 1024, 0, stream>>>(src, dst, ew, pdeg, pcnt);
    reduce_kernel<<<(NN + B - 1) / B, B, 0, stream>>>(pdeg, pcnt, cnt, dis, diag);
    scanA_kernel<<<NB, 256, 0, stream>>>(cnt, bsum);
    scanB_kernel<<<1, 64, 0, stream>>>(bsum, boff, row_start);
    scanC_kernel<<<NB, 256, 0, stream>>>(cnt, boff, row_start);
    fill_kernel<<<NCHUNK * NSLICE, 1024, 0, stream>>>(src, dst, ew, dis, row_start, pcnt,
                                                      csr_src, csr_w);

    // ---------------- layer 1 (Fin=128, Hout=64) ----------------
    int g1 = (NN * HH + B - 1) / B;
    gemm_accum_kernel<<<g1, B, 0, stream>>>(x, W1 + 0 * FF * HH, b1, Zacc, NN, FF, HH, 1);
    prop_kernel<FF><<<NN, FF, 0, stream>>>(x, x, diag, row_start, csr_src, csr_w, T1, 1.f, 0.f);
    gemm_accum_kernel<<<g1, B, 0, stream>>>(T1, W1 + 1 * FF * HH, b1, Zacc, NN, FF, HH, 0);
    prop_kernel<FF><<<NN, FF, 0, stream>>>(T1, x, diag, row_start, csr_src, csr_w, T2, 2.f, -1.f);
    gemm_accum_kernel<<<g1, B, 0, stream>>>(T2, W1 + 2 * FF * HH, b1, Zacc, NN, FF, HH, 0);
    prop_kernel<FF><<<NN, FF, 0, stream>>>(T2, T1, diag, row_start, csr_src, csr_w, T3, 2.f, -1.f);
    gemm_accum_kernel<<<g1, B, 0, stream>>>(T3, W1 + 3 * FF * HH, b1, Zacc, NN, FF, HH, 0);
    relu_kernel<<<(NN * HH + B - 1) / B, B, 0, stream>>>(Zacc, NN * HH);
    float* h = Zacc;

    // ---------------- layer 2 (Fin=64, Hout=40), reuse T buffers as S ----------------
    float* S1 = T1; float* S2 = T2; float* S3 = T3;
    int g2 = (NN * CC + B - 1) / B;
    gemm_accum_kernel<<<g2, B, 0, stream>>>(h, W2 + 0 * HH * CC, b2, out, NN, HH, CC, 1);
    prop_kernel<HH><<<NN, HH, 0, stream>>>(h, h, diag, row_start, csr_src, csr_w, S1, 1.f, 0.f);
    gemm_accum_kernel<<<g2, B, 0, stream>>>(S1, W2 + 1 * HH * CC, b2, out, NN, HH, CC, 0);
    prop_kernel<HH><<<NN, HH, 0, stream>>>(S1, h, diag, row_start, csr_src, csr_w, S2, 2.f, -1.f);
    gemm_accum_kernel<<<g2, B, 0, stream>>>(S2, W2 + 2 * HH * CC, b2, out, NN, HH, CC, 0);
    prop_kernel<HH><<<NN, HH, 0, stream>>>(S2, S1, diag, row_start, csr_src, csr_w, S3, 2.f, -1.f);
    gemm_accum_kernel<<<g2, B, 0, stream>>>(S3, W2 + 3 * HH * CC, b2, out, NN, HH, CC, 0);
}

// Round 4
// 785.484 us; speedup vs baseline: 2.1441x; 1.4917x over previous
//
#include <hip/hip_runtime.h>

// Problem constants (from reference)
#define NN 50000
#define EE 1600000
#define FF 128
#define HH 64
#define CC 40
#define KK 4

// Setup partitioning: 32 edge-chunks x 8 node-slices = 256 blocks, LDS histograms
#define NCHUNK 32
#define NSLICE 8
#define CHUNK_E (EE / NCHUNK)   // 50000
#define SLICE_N (NN / NSLICE)   // 6250
#define NB 196                  // ceil(NN/256) scan blocks

// ---------- setup: LDS-privatized histograms (zero global atomics) ----------
__global__ __launch_bounds__(1024) void partial_hist_kernel(
    const int* __restrict__ src, const int* __restrict__ dst,
    const float* __restrict__ w,
    float* __restrict__ pdeg, int* __restrict__ pcnt) {
    __shared__ float ldeg[SLICE_N];
    __shared__ int   lcnt[SLICE_N];
    int s = blockIdx.x % NSLICE;
    int c = blockIdx.x / NSLICE;
    int base = s * SLICE_N;
    for (int i = threadIdx.x; i < SLICE_N; i += 1024) { ldeg[i] = 0.f; lcnt[i] = 0; }
    __syncthreads();
    int e0 = c * CHUNK_E;
    for (int e = e0 + threadIdx.x; e < e0 + CHUNK_E; e += 1024) {
        int se = src[e], de = dst[e];
        unsigned us = (unsigned)(se - base), ud = (unsigned)(de - base);
        if (us < SLICE_N) atomicAdd(&ldeg[us], w[e]);
        if (ud < SLICE_N) atomicAdd(&lcnt[ud], 1);
    }
    __syncthreads();
    for (int i = threadIdx.x; i < SLICE_N; i += 1024) {
        pdeg[(size_t)c * NN + base + i] = ldeg[i];
        pcnt[(size_t)c * NN + base + i] = lcnt[i];
    }
}

__global__ void reduce_kernel(const float* __restrict__ pdeg, int* __restrict__ pcnt,
                              int* __restrict__ cnt, float* __restrict__ dis,
                              float* __restrict__ diag) {
    int n = blockIdx.x * blockDim.x + threadIdx.x;
    if (n >= NN) return;
    float dsum = 0.f;
    #pragma unroll
    for (int c = 0; c < NCHUNK; ++c) dsum += pdeg[(size_t)c * NN + n];
    int run = 0;
    #pragma unroll
    for (int c = 0; c < NCHUNK; ++c) {
        int t = pcnt[(size_t)c * NN + n];
        pcnt[(size_t)c * NN + n] = run;
        run += t;
    }
    cnt[n] = run;
    dis[n]  = (dsum > 0.f) ? rsqrtf(fmaxf(dsum, 1e-12f)) : 0.f;
    diag[n] = (dsum > 0.f) ? 0.f : -1.f;
}

// ---------- 3-kernel exclusive scan of cnt[NN] -> row_start[NN+1] ----------
__global__ void scanA_kernel(const int* __restrict__ cnt, int* __restrict__ bsum) {
    __shared__ int sh[256];
    int i = blockIdx.x * 256 + threadIdx.x;
    sh[threadIdx.x] = (i < NN) ? cnt[i] : 0;
    __syncthreads();
    for (int off = 128; off > 0; off >>= 1) {
        if (threadIdx.x < off) sh[threadIdx.x] += sh[threadIdx.x + off];
        __syncthreads();
    }
    if (threadIdx.x == 0) bsum[blockIdx.x] = sh[0];
}

__global__ void scanB_kernel(const int* __restrict__ bsum, int* __restrict__ boff,
                             int* __restrict__ row_start) {
    if (threadIdx.x == 0) {
        int run = 0;
        for (int b = 0; b < NB; ++b) { boff[b] = run; run += bsum[b]; }
        row_start[NN] = run;
    }
}

__global__ void scanC_kernel(const int* __restrict__ cnt, const int* __restrict__ boff,
                             int* __restrict__ row_start) {
    __shared__ int sh[256];
    int t = threadIdx.x;
    int i = blockIdx.x * 256 + t;
    int v = (i < NN) ? cnt[i] : 0;
    sh[t] = v;
    __syncthreads();
    for (int off = 1; off < 256; off <<= 1) {
        int x = (t >= off) ? sh[t - off] : 0;
        __syncthreads();
        sh[t] += x;
        __syncthreads();
    }
    if (i < NN) row_start[i] = boff[blockIdx.x] + sh[t] - v;
}

// ---------- CSR fill with LDS cursors (zero global atomics) ----------
__global__ __launch_bounds__(1024) void fill_kernel(
    const int* __restrict__ src, const int* __restrict__ dst,
    const float* __restrict__ w, const float* __restrict__ dis,
    const int* __restrict__ row_start, const int* __restrict__ pcnt,
    int* __restrict__ csr_src, float* __restrict__ csr_w) {
    __shared__ int lcur[SLICE_N];
    int s = blockIdx.x % NSLICE;
    int c = blockIdx.x / NSLICE;
    int base = s * SLICE_N;
    for (int i = threadIdx.x; i < SLICE_N; i += 1024) lcur[i] = 0;
    __syncthreads();
    int e0 = c * CHUNK_E;
    for (int e = e0 + threadIdx.x; e < e0 + CHUNK_E; e += 1024) {
        int de = dst[e];
        unsigned ud = (unsigned)(de - base);
        if (ud < SLICE_N) {
            int se = src[e];
            int off = atomicAdd(&lcur[ud], 1);
            int pos = row_start[de] + pcnt[(size_t)c * NN + de] + off;
            csr_src[pos] = se;
            csr_w[pos] = -dis[se] * w[e] * dis[de];
        }
    }
}

// ---------- propagation: out = alpha*(diag*h + sum_in w*h[src]) + beta*prev ----------
// one block per node, blockDim == F; edge loop unrolled x16 for MLP (latency-bound).
template <int F>
__global__ void prop_kernel(const float* __restrict__ h, const float* __restrict__ prev,
                            const float* __restrict__ diag, const int* __restrict__ row_start,
                            const int* __restrict__ csr_src, const float* __restrict__ csr_w,
                            float* __restrict__ out, float alpha, float beta) {
    int n = blockIdx.x;
    int f = threadIdx.x;
    size_t nf = (size_t)n * F + f;
    float acc = diag[n] * h[nf];
    int j0 = row_start[n], j1 = row_start[n + 1];
    int j = j0;
    for (; j + 16 <= j1; j += 16) {
        int   s[16];
        float w[16];
        #pragma unroll
        for (int u = 0; u < 16; ++u) { s[u] = csr_src[j + u]; w[u] = csr_w[j + u]; }
        float v[16];
        #pragma unroll
        for (int u = 0; u < 16; ++u) v[u] = h[(size_t)s[u] * F + f];
        #pragma unroll
        for (int u = 0; u < 16; ++u) acc = fmaf(w[u], v[u], acc);
    }
    for (; j + 8 <= j1; j += 8) {
        int   s[8];
        float w[8];
        #pragma unroll
        for (int u = 0; u < 8; ++u) { s[u] = csr_src[j + u]; w[u] = csr_w[j + u]; }
        float v[8];
        #pragma unroll
        for (int u = 0; u < 8; ++u) v[u] = h[(size_t)s[u] * F + f];
        #pragma unroll
        for (int u = 0; u < 8; ++u) acc = fmaf(w[u], v[u], acc);
    }
    for (; j < j1; ++j)
        acc = fmaf(csr_w[j], h[(size_t)csr_src[j] * F + f], acc);
    float r = alpha * acc;
    if (beta != 0.f) r = fmaf(beta, prev[nf], r);
    out[nf] = r;
}

// ---------- fused layer-1 GEMM: h = relu([x|T1|T2|T3] @ W1 + b1) ----------
// 64-row x 64-col tile, BK=32, 256 threads, 4x4 micro-tile, bias+relu epilogue.
__global__ __launch_bounds__(256) void gemm1_kernel(
    const float* __restrict__ A0, const float* __restrict__ A1,
    const float* __restrict__ A2, const float* __restrict__ A3,
    const float* __restrict__ W, const float* __restrict__ bias,
    float* __restrict__ out) {
    __shared__ float As[64][36];   // [m][k], pad 32->36 keeps f4 stores 16B-aligned
    __shared__ float Bs[32][64];   // [k][j]
    const float* bufs[4] = {A0, A1, A2, A3};
    int t = threadIdx.x;
    int m0 = blockIdx.x * 64;
    int tr = t / 16, tc = t % 16;          // compute: 4 rows x 4 cols per thread
    int kq = t % 8, ms = t / 8;            // A staging
    int jq = t % 16, ks = t / 16;          // B staging
    float acc[4][4] = {};
    for (int kb = 0; kb < 16; ++kb) {
        const float* Ab = bufs[kb >> 2];
        int k0 = (kb & 3) * 32;
        const float* Wb = W + (size_t)kb * 32 * HH;   // global k row = kb*32
        __syncthreads();
        #pragma unroll
        for (int p = 0; p < 2; ++p) {
            int m = ms + 32 * p;
            int row = m0 + m;
            float4 v = make_float4(0.f, 0.f, 0.f, 0.f);
            if (row < NN) v = *(const float4*)(Ab + (size_t)row * FF + k0 + kq * 4);
            *(float4*)&As[m][kq * 4] = v;
        }
        #pragma unroll
        for (int p = 0; p < 2; ++p) {
            int k = ks + 16 * p;
            float4 v = *(const float4*)(Wb + k * HH + jq * 4);
            *(float4*)&Bs[k][jq * 4] = v;
        }
        __syncthreads();
        #pragma unroll 8
        for (int k = 0; k < 32; ++k) {
            float a0 = As[tr * 4 + 0][k], a1 = As[tr * 4 + 1][k];
            float a2 = As[tr * 4 + 2][k], a3 = As[tr * 4 + 3][k];
            float4 b = *(float4*)&Bs[k][tc * 4];
            acc[0][0] = fmaf(a0, b.x, acc[0][0]); acc[0][1] = fmaf(a0, b.y, acc[0][1]);
            acc[0][2] = fmaf(a0, b.z, acc[0][2]); acc[0][3] = fmaf(a0, b.w, acc[0][3]);
            acc[1][0] = fmaf(a1, b.x, acc[1][0]); acc[1][1] = fmaf(a1, b.y, acc[1][1]);
            acc[1][2] = fmaf(a1, b.z, acc[1][2]); acc[1][3] = fmaf(a1, b.w, acc[1][3]);
            acc[2][0] = fmaf(a2, b.x, acc[2][0]); acc[2][1] = fmaf(a2, b.y, acc[2][1]);
            acc[2][2] = fmaf(a2, b.z, acc[2][2]); acc[2][3] = fmaf(a2, b.w, acc[2][3]);
            acc[3][0] = fmaf(a3, b.x, acc[3][0]); acc[3][1] = fmaf(a3, b.y, acc[3][1]);
            acc[3][2] = fmaf(a3, b.z, acc[3][2]); acc[3][3] = fmaf(a3, b.w, acc[3][3]);
        }
    }
    int j = tc * 4;
    float4 bv = *(const float4*)(bias + j);
    #pragma unroll
    for (int r = 0; r < 4; ++r) {
        int n = m0 + tr * 4 + r;
        if (n < NN) {
            float4 z;
            z.x = fmaxf(acc[r][0] + bv.x, 0.f);
            z.y = fmaxf(acc[r][1] + bv.y, 0.f);
            z.z = fmaxf(acc[r][2] + bv.z, 0.f);
            z.w = fmaxf(acc[r][3] + bv.w, 0.f);
            *(float4*)(out + (size_t)n * HH + j) = z;
        }
    }
}

// ---------- fused layer-2 GEMM: out = [h|S1|S2|S3] @ W2 + b2 ----------
// 128-row x 40-col tile, BK=32, 256 threads, 4x5 micro-tile.
__global__ __launch_bounds__(256) void gemm2_kernel(
    const float* __restrict__ A0, const float* __restrict__ A1,
    const float* __restrict__ A2, const float* __restrict__ A3,
    const float* __restrict__ W, const float* __restrict__ bias,
    float* __restrict__ out) {
    __shared__ float As[128][36];
    __shared__ float Bs[32][40];
    const float* bufs[4] = {A0, A1, A2, A3};
    int t = threadIdx.x;
    int m0 = blockIdx.x * 128;
    int tr = t / 8, tc = t % 8;            // compute: 4 rows x 5 cols per thread
    int kq = t % 8, ms = t / 8;            // A staging
    float acc[4][5] = {};
    for (int kb = 0; kb < 8; ++kb) {
        const float* Ab = bufs[kb >> 1];
        int k0 = (kb & 1) * 32;
        const float* Wb = W + (size_t)kb * 32 * CC;
        __syncthreads();
        #pragma unroll
        for (int p = 0; p < 4; ++p) {
            int m = ms + 32 * p;
            int row = m0 + m;
            float4 v = make_float4(0.f, 0.f, 0.f, 0.f);
            if (row < NN) v = *(const float4*)(Ab + (size_t)row * HH + k0 + kq * 4);
            *(float4*)&As[m][kq * 4] = v;
        }
        for (int i = t; i < 32 * CC; i += 256)
            ((float*)Bs)[i] = Wb[i];       // Bs[k][j], contiguous
        __syncthreads();
        #pragma unroll 4
        for (int k = 0; k < 32; ++k) {
            float a0 = As[tr * 4 + 0][k], a1 = As[tr * 4 + 1][k];
            float a2 = As[tr * 4 + 2][k], a3 = As[tr * 4 + 3][k];
            #pragma unroll
            for (int c = 0; c < 5; ++c) {
                float b = Bs[k][tc * 5 + c];
                acc[0][c] = fmaf(a0, b, acc[0][c]);
                acc[1][c] = fmaf(a1, b, acc[1][c]);
                acc[2][c] = fmaf(a2, b, acc[2][c]);
                acc[3][c] = fmaf(a3, b, acc[3][c]);
            }
        }
    }
    #pragma unroll
    for (int r = 0; r < 4; ++r) {
        int n = m0 + tr * 4 + r;
        if (n < NN) {
            #pragma unroll
            for (int c = 0; c < 5; ++c) {
                int j = tc * 5 + c;
                out[(size_t)n * CC + j] = acc[r][c] + bias[j];
            }
        }
    }
}

// ---------- launcher ----------
extern "C" void kernel_launch(void* const* d_in, const int* in_sizes, int n_in,
                              void* d_out, int out_size, void* d_ws, size_t ws_size,
                              hipStream_t stream) {
    const float* x    = (const float*)d_in[0];         // [N, F]
    const int*   eidx = (const int*)d_in[1];           // [2, E]
    const float* ew   = (const float*)d_in[2];         // [E]
    const float* W1   = (const float*)d_in[3];         // [K*F, H]
    const float* b1   = (const float*)d_in[4];         // [H]
    const float* W2   = (const float*)d_in[5];         // [K*H, C]
    const float* b2   = (const float*)d_in[6];         // [C]
    float* out = (float*)d_out;                        // [N, C]

    const int* src = eidx;        // edge_index[0]
    const int* dst = eidx + EE;   // edge_index[1]

    // workspace carve-up (floats then ints)
    float* p = (float*)d_ws;
    float* dis    = p;             p += NN;
    float* diag   = p;             p += NN;
    float* csr_w  = p;             p += EE;
    float* T1     = p;             p += (size_t)NN * FF;
    float* T2     = p;             p += (size_t)NN * FF;
    float* T3     = p;             p += (size_t)NN * FF;
    float* h      = p;             p += (size_t)NN * HH;
    int* cnt       = (int*)p;
    int* row_start = cnt + NN;          // NN+1
    int* csr_src   = row_start + NN + 1;
    int* bsum      = csr_src + EE;      // NB
    int* boff      = bsum + NB;         // NB

    // Partials alias T2/T3: dead before the props that write T2/T3 run.
    float* pdeg = T2;            // NCHUNK*NN floats (6.4 MB of T2's 25.6 MB)
    int*   pcnt = (int*)T3;

    const int B = 256;
    partial_hist_kernel<<<NCHUNK * NSLICE, 1024, 0, stream>>>(src, dst, ew, pdeg, pcnt);
    reduce_kernel<<<(NN + B - 1) / B, B, 0, stream>>>(pdeg, pcnt, cnt, dis, diag);
    scanA_kernel<<<NB, 256, 0, stream>>>(cnt, bsum);
    scanB_kernel<<<1, 64, 0, stream>>>(bsum, boff, row_start);
    scanC_kernel<<<NB, 256, 0, stream>>>(cnt, boff, row_start);
    fill_kernel<<<NCHUNK * NSLICE, 1024, 0, stream>>>(src, dst, ew, dis, row_start, pcnt,
                                                      csr_src, csr_w);

    // ---------------- layer 1: props then one fused GEMM (+bias+relu) ----------------
    prop_kernel<FF><<<NN, FF, 0, stream>>>(x, x, diag, row_start, csr_src, csr_w, T1, 1.f, 0.f);
    prop_kernel<FF><<<NN, FF, 0, stream>>>(T1, x, diag, row_start, csr_src, csr_w, T2, 2.f, -1.f);
    prop_kernel<FF><<<NN, FF, 0, stream>>>(T2, T1, diag, row_start, csr_src, csr_w, T3, 2.f, -1.f);
    gemm1_kernel<<<(NN + 63) / 64, 256, 0, stream>>>(x, T1, T2, T3, W1, b1, h);

    // ---------------- layer 2: props then fused GEMM (+bias) ----------------
    float* S1 = T1; float* S2 = T2; float* S3 = T3;
    prop_kernel<HH><<<NN, HH, 0, stream>>>(h, h, diag, row_start, csr_src, csr_w, S1, 1.f, 0.f);
    prop_kernel<HH><<<NN, HH, 0, stream>>>(S1, h, diag, row_start, csr_src, csr_w, S2, 2.f, -1.f);
    prop_kernel<HH><<<NN, HH, 0, stream>>>(S2, S1, diag, row_start, csr_src, csr_w, S3, 2.f, -1.f);
    gemm2_kernel<<<(NN + 127) / 128, 256, 0, stream>>>(h, S1, S2, S3, W2, b2, out);
}

// Round 5
// 613.873 us; speedup vs baseline: 2.7434x; 1.2796x over previous
//
#include <hip/hip_runtime.h>

// Problem constants (from reference)
#define NN 50000
#define EE 1600000
#define FF 128
#define HH 64
#define CC 40

// Setup partitioning: 64 edge-chunks x 4 node-slices = 256 blocks, LDS histograms
#define NCHUNK 64
#define NSLICE 4
#define CHUNK_E (EE / NCHUNK)   // 25000
#define SLICE_N (NN / NSLICE)   // 12500
#define NB 196                  // ceil(NN/256) scan blocks

// ---------- setup: LDS-privatized histograms (zero global atomics) ----------
__global__ __launch_bounds__(1024) void partial_hist_kernel(
    const int* __restrict__ src, const int* __restrict__ dst,
    const float* __restrict__ w,
    float* __restrict__ pdeg, int* __restrict__ pcnt) {
    __shared__ float ldeg[SLICE_N];
    __shared__ int   lcnt[SLICE_N];
    int s = blockIdx.x % NSLICE;
    int c = blockIdx.x / NSLICE;
    int base = s * SLICE_N;
    for (int i = threadIdx.x; i < SLICE_N; i += 1024) { ldeg[i] = 0.f; lcnt[i] = 0; }
    __syncthreads();
    int e0 = c * CHUNK_E;
    for (int e = e0 + threadIdx.x; e < e0 + CHUNK_E; e += 1024) {
        int se = src[e], de = dst[e];
        unsigned us = (unsigned)(se - base), ud = (unsigned)(de - base);
        if (us < SLICE_N) atomicAdd(&ldeg[us], w[e]);
        if (ud < SLICE_N) atomicAdd(&lcnt[ud], 1);
    }
    __syncthreads();
    for (int i = threadIdx.x; i < SLICE_N; i += 1024) {
        pdeg[(size_t)c * NN + base + i] = ldeg[i];
        pcnt[(size_t)c * NN + base + i] = lcnt[i];
    }
}

__global__ void reduce_kernel(const float* __restrict__ pdeg, int* __restrict__ pcnt,
                              int* __restrict__ cnt, float* __restrict__ dis,
                              float* __restrict__ diag) {
    int n = blockIdx.x * blockDim.x + threadIdx.x;
    if (n >= NN) return;
    float dsum = 0.f;
    for (int c = 0; c < NCHUNK; ++c) dsum += pdeg[(size_t)c * NN + n];
    int run = 0;
    for (int c = 0; c < NCHUNK; ++c) {
        int t = pcnt[(size_t)c * NN + n];
        pcnt[(size_t)c * NN + n] = run;
        run += t;
    }
    cnt[n] = run;
    dis[n]  = (dsum > 0.f) ? rsqrtf(fmaxf(dsum, 1e-12f)) : 0.f;
    diag[n] = (dsum > 0.f) ? 0.f : -1.f;
}

// ---------- 3-kernel exclusive scan of cnt[NN] -> row_start[NN+1] ----------
__global__ void scanA_kernel(const int* __restrict__ cnt, int* __restrict__ bsum) {
    __shared__ int sh[256];
    int i = blockIdx.x * 256 + threadIdx.x;
    sh[threadIdx.x] = (i < NN) ? cnt[i] : 0;
    __syncthreads();
    for (int off = 128; off > 0; off >>= 1) {
        if (threadIdx.x < off) sh[threadIdx.x] += sh[threadIdx.x + off];
        __syncthreads();
    }
    if (threadIdx.x == 0) bsum[blockIdx.x] = sh[0];
}

__global__ void scanB_kernel(const int* __restrict__ bsum, int* __restrict__ boff,
                             int* __restrict__ row_start) {
    if (threadIdx.x == 0) {
        int run = 0;
        for (int b = 0; b < NB; ++b) { boff[b] = run; run += bsum[b]; }
        row_start[NN] = run;
    }
}

__global__ void scanC_kernel(const int* __restrict__ cnt, const int* __restrict__ boff,
                             int* __restrict__ row_start) {
    __shared__ int sh[256];
    int t = threadIdx.x;
    int i = blockIdx.x * 256 + t;
    int v = (i < NN) ? cnt[i] : 0;
    sh[t] = v;
    __syncthreads();
    for (int off = 1; off < 256; off <<= 1) {
        int x = (t >= off) ? sh[t - off] : 0;
        __syncthreads();
        sh[t] += x;
        __syncthreads();
    }
    if (i < NN) row_start[i] = boff[blockIdx.x] + sh[t] - v;
}

// ---------- CSR fill with LDS cursors (zero global atomics) ----------
__global__ __launch_bounds__(1024) void fill_kernel(
    const int* __restrict__ src, const int* __restrict__ dst,
    const float* __restrict__ w, const float* __restrict__ dis,
    const int* __restrict__ row_start, const int* __restrict__ pcnt,
    int* __restrict__ csr_src, float* __restrict__ csr_w) {
    __shared__ int lcur[SLICE_N];
    int s = blockIdx.x % NSLICE;
    int c = blockIdx.x / NSLICE;
    int base = s * SLICE_N;
    for (int i = threadIdx.x; i < SLICE_N; i += 1024) lcur[i] = 0;
    __syncthreads();
    int e0 = c * CHUNK_E;
    for (int e = e0 + threadIdx.x; e < e0 + CHUNK_E; e += 1024) {
        int de = dst[e];
        unsigned ud = (unsigned)(de - base);
        if (ud < SLICE_N) {
            int se = src[e];
            int off = atomicAdd(&lcur[ud], 1);
            int pos = row_start[de] + pcnt[(size_t)c * NN + de] + off;
            csr_src[pos] = se;
            csr_w[pos] = -dis[se] * w[e] * dis[de];
        }
    }
}

// ---------- generalized propagation ----------
// out[n,f] = alphaL*(diag[n]*a[n,f] + sum_in w*a[src,f]) + beta1*p1[n,f] + beta2*p2[n,f]
//            (+ bias[f]) (+ relu)    -- one wave per node, lane = feature.
// FACT: active gather lanes (64, or 48 for padded layer-2 vectors).
template <int FACT>
__global__ __launch_bounds__(256) void prop2_kernel(
    const float* __restrict__ a, int aStride, float alphaL,
    const float* __restrict__ p1, float beta1,
    const float* __restrict__ p2, float beta2, int pStride,
    const float* __restrict__ bias, int doRelu, int FOUT, int outStride,
    const float* __restrict__ diag, const int* __restrict__ rs,
    const int* __restrict__ csr_src, const float* __restrict__ csr_w,
    float* __restrict__ out) {
    int lane = threadIdx.x & 63;
    int wave = threadIdx.x >> 6;
    int n = blockIdx.x * 4 + wave;   // NN divisible by 4
    int f = lane;
    float acc = 0.f;
    if (f < FACT) {
        acc = diag[n] * a[(size_t)n * aStride + f];
        int j0 = rs[n], j1 = rs[n + 1];
        int j = j0;
        for (; j + 8 <= j1; j += 8) {
            int   s[8];
            float w[8];
            #pragma unroll
            for (int u = 0; u < 8; ++u) { s[u] = csr_src[j + u]; w[u] = csr_w[j + u]; }
            float v[8];
            #pragma unroll
            for (int u = 0; u < 8; ++u) v[u] = a[(size_t)s[u] * aStride + f];
            #pragma unroll
            for (int u = 0; u < 8; ++u) acc = fmaf(w[u], v[u], acc);
        }
        for (; j < j1; ++j)
            acc = fmaf(csr_w[j], a[(size_t)csr_src[j] * aStride + f], acc);
    }
    if (f < FOUT) {
        float r = alphaL * acc + beta1 * p1[(size_t)n * pStride + f];
        if (beta2 != 0.f) r = fmaf(beta2, p2[(size_t)n * pStride + f], r);
        if (bias) r += bias[f];
        if (doRelu) r = fmaxf(r, 0.f);
        out[(size_t)n * outStride + f] = r;
    }
}

// ---------- GEMM1: Y[n, ct*64+j] = sum_f x[n,f] * W1[(ct*128+f)*64 + j] ----------
// grid (m-tiles, 4); 64x64 tile, BK=32, 4x4 micro-tile.
__global__ __launch_bounds__(256) void gemm1_kernel(
    const float* __restrict__ x, const float* __restrict__ W,
    float* __restrict__ Y) {
    __shared__ float As[64][36];
    __shared__ float Bs[32][64];
    int t = threadIdx.x;
    int m0 = blockIdx.x * 64;
    int ct = blockIdx.y;               // which y_k
    int tr = t / 16, tc = t % 16;
    int kq = t % 8,  ms = t / 8;
    int jb = t % 16, fb = t / 16;
    float acc[4][4] = {};
    for (int kb = 0; kb < 4; ++kb) {
        __syncthreads();
        #pragma unroll
        for (int p = 0; p < 2; ++p) {
            int m = ms + 32 * p;
            int row = m0 + m;
            float4 vv = make_float4(0.f, 0.f, 0.f, 0.f);
            if (row < NN) vv = *(const float4*)(x + (size_t)row * FF + kb * 32 + kq * 4);
            *(float4*)&As[m][kq * 4] = vv;
        }
        const float* Wb = W + ((size_t)ct * 128 + kb * 32) * HH;
        #pragma unroll
        for (int p = 0; p < 2; ++p) {
            int fi = fb + 16 * p;
            float4 vv = *(const float4*)(Wb + fi * HH + jb * 4);
            *(float4*)&Bs[fi][jb * 4] = vv;
        }
        __syncthreads();
        #pragma unroll 8
        for (int k = 0; k < 32; ++k) {
            float a0 = As[tr * 4 + 0][k], a1 = As[tr * 4 + 1][k];
            float a2 = As[tr * 4 + 2][k], a3 = As[tr * 4 + 3][k];
            float4 b = *(float4*)&Bs[k][tc * 4];
            acc[0][0] = fmaf(a0, b.x, acc[0][0]); acc[0][1] = fmaf(a0, b.y, acc[0][1]);
            acc[0][2] = fmaf(a0, b.z, acc[0][2]); acc[0][3] = fmaf(a0, b.w, acc[0][3]);
            acc[1][0] = fmaf(a1, b.x, acc[1][0]); acc[1][1] = fmaf(a1, b.y, acc[1][1]);
            acc[1][2] = fmaf(a1, b.z, acc[1][2]); acc[1][3] = fmaf(a1, b.w, acc[1][3]);
            acc[2][0] = fmaf(a2, b.x, acc[2][0]); acc[2][1] = fmaf(a2, b.y, acc[2][1]);
            acc[2][2] = fmaf(a2, b.z, acc[2][2]); acc[2][3] = fmaf(a2, b.w, acc[2][3]);
            acc[3][0] = fmaf(a3, b.x, acc[3][0]); acc[3][1] = fmaf(a3, b.y, acc[3][1]);
            acc[3][2] = fmaf(a3, b.z, acc[3][2]); acc[3][3] = fmaf(a3, b.w, acc[3][3]);
        }
    }
    #pragma unroll
    for (int r = 0; r < 4; ++r) {
        int n = m0 + tr * 4 + r;
        if (n < NN)
            *(float4*)(Y + (size_t)n * 256 + ct * 64 + tc * 4) =
                make_float4(acc[r][0], acc[r][1], acc[r][2], acc[r][3]);
    }
}

// ---------- GEMM2: Y2[n*192 + kt*48 + j] = sum_f h[n,f] * W2[(kt*64+f)*40 + j] ----------
// grid (m-tiles, 4); 128x40 tile, BK=32, 4x5 micro-tile.
__global__ __launch_bounds__(256) void gemm2_kernel(
    const float* __restrict__ h, const float* __restrict__ W,
    float* __restrict__ Y2) {
    __shared__ float As[128][36];
    __shared__ float Bs[32][40];
    int t = threadIdx.x;
    int m0 = blockIdx.x * 128;
    int kt = blockIdx.y;
    int tr = t / 8, tc = t % 8;
    int kq = t % 8, ms = t / 8;
    float acc[4][5] = {};
    for (int kb = 0; kb < 2; ++kb) {
        __syncthreads();
        #pragma unroll
        for (int p = 0; p < 4; ++p) {
            int m = ms + 32 * p;
            int row = m0 + m;
            float4 vv = make_float4(0.f, 0.f, 0.f, 0.f);
            if (row < NN) vv = *(const float4*)(h + (size_t)row * HH + kb * 32 + kq * 4);
            *(float4*)&As[m][kq * 4] = vv;
        }
        const float* Wb = W + ((size_t)kt * 64 + kb * 32) * CC;
        for (int i = t; i < 32 * CC; i += 256) ((float*)Bs)[i] = Wb[i];
        __syncthreads();
        #pragma unroll 4
        for (int k = 0; k < 32; ++k) {
            float a0 = As[tr * 4 + 0][k], a1 = As[tr * 4 + 1][k];
            float a2 = As[tr * 4 + 2][k], a3 = As[tr * 4 + 3][k];
            #pragma unroll
            for (int c = 0; c < 5; ++c) {
                float b = Bs[k][tc * 5 + c];
                acc[0][c] = fmaf(a0, b, acc[0][c]);
                acc[1][c] = fmaf(a1, b, acc[1][c]);
                acc[2][c] = fmaf(a2, b, acc[2][c]);
                acc[3][c] = fmaf(a3, b, acc[3][c]);
            }
        }
    }
    #pragma unroll
    for (int r = 0; r < 4; ++r) {
        int n = m0 + tr * 4 + r;
        if (n < NN) {
            #pragma unroll
            for (int c = 0; c < 5; ++c)
                Y2[(size_t)n * 192 + kt * 48 + tc * 5 + c] = acc[r][c];
        }
    }
}

// ---------- launcher ----------
extern "C" void kernel_launch(void* const* d_in, const int* in_sizes, int n_in,
                              void* d_out, int out_size, void* d_ws, size_t ws_size,
                              hipStream_t stream) {
    const float* x    = (const float*)d_in[0];
    const int*   eidx = (const int*)d_in[1];
    const float* ew   = (const float*)d_in[2];
    const float* W1   = (const float*)d_in[3];
    const float* b1   = (const float*)d_in[4];
    const float* W2   = (const float*)d_in[5];
    const float* b2   = (const float*)d_in[6];
    float* out = (float*)d_out;

    const int* src = eidx;
    const int* dst = eidx + EE;

    // workspace carve-up (64-float aligned blocks)
    float* p = (float*)d_ws;
    float* dis   = p;  p += ((NN + 63) / 64) * 64;
    float* diag  = p;  p += ((NN + 63) / 64) * 64;
    float* csr_w = p;  p += EE;
    float* Y     = p;  p += (size_t)NN * 256;   // layer-1 y_k slabs; aliased by Y2, partials
    float* u     = p;  p += (size_t)NN * 64;
    float* v     = p;  p += (size_t)NN * 64;
    float* h     = p;  p += (size_t)NN * 64;
    int* cnt       = (int*)p;
    int* row_start = cnt + NN;            // NN+1
    int* csr_src   = row_start + NN + 1;
    int* bsum      = csr_src + EE;
    int* boff      = bsum + NB;

    // aliases (lifetimes are stream-ordered disjoint)
    float* pdeg = Y;                       // NCHUNK*NN = 12.8 MB
    int*   pcnt = (int*)(Y + (size_t)NCHUNK * NN);
    float* Y2 = Y;                         // [N,192] = 38.4 MB inside Y's 51.2
    float* u2 = u;                         // [N,48] stride inside [N,64]
    float* v2 = v;

    const int B = 256;
    partial_hist_kernel<<<NCHUNK * NSLICE, 1024, 0, stream>>>(src, dst, ew, pdeg, pcnt);
    reduce_kernel<<<(NN + B - 1) / B, B, 0, stream>>>(pdeg, pcnt, cnt, dis, diag);
    scanA_kernel<<<NB, 256, 0, stream>>>(cnt, bsum);
    scanB_kernel<<<1, 64, 0, stream>>>(bsum, boff, row_start);
    scanC_kernel<<<NB, 256, 0, stream>>>(cnt, boff, row_start);
    fill_kernel<<<NCHUNK * NSLICE, 1024, 0, stream>>>(src, dst, ew, dis, row_start, pcnt,
                                                      csr_src, csr_w);

    int pgrid = NN / 4;

    // ---- layer 1: project first (Y = x@W1 per-k), then 3 props in 64-dim ----
    gemm1_kernel<<<dim3((NN + 63) / 64, 4), 256, 0, stream>>>(x, W1, Y);
    // u = 4*Lhat(y3) + 2*y2
    prop2_kernel<64><<<pgrid, 256, 0, stream>>>(Y + 192, 256, 4.f, Y + 128, 2.f,
                                                nullptr, 0.f, 256, nullptr, 0, 64, 64,
                                                diag, row_start, csr_src, csr_w, u);
    // v = Lhat(u) + y1 - 3*y3
    prop2_kernel<64><<<pgrid, 256, 0, stream>>>(u, 64, 1.f, Y + 64, 1.f,
                                                Y + 192, -3.f, 256, nullptr, 0, 64, 64,
                                                diag, row_start, csr_src, csr_w, v);
    // h = relu(Lhat(v) + y0 - y2 + b1)
    prop2_kernel<64><<<pgrid, 256, 0, stream>>>(v, 64, 1.f, Y, 1.f,
                                                Y + 128, -1.f, 256, b1, 1, 64, 64,
                                                diag, row_start, csr_src, csr_w, h);

    // ---- layer 2: project (Y2 = h@W2 per-k, stride-48 padded), 3 props in 40-dim ----
    gemm2_kernel<<<dim3((NN + 127) / 128, 4), 256, 0, stream>>>(h, W2, Y2);
    // u2 = 4*Lhat(y'3) + 2*y'2
    prop2_kernel<48><<<pgrid, 256, 0, stream>>>(Y2 + 144, 192, 4.f, Y2 + 96, 2.f,
                                                nullptr, 0.f, 192, nullptr, 0, 48, 48,
                                                diag, row_start, csr_src, csr_w, u2);
    // v2 = Lhat(u2) + y'1 - 3*y'3
    prop2_kernel<48><<<pgrid, 256, 0, stream>>>(u2, 48, 1.f, Y2 + 48, 1.f,
                                                Y2 + 144, -3.f, 192, nullptr, 0, 48, 48,
                                                diag, row_start, csr_src, csr_w, v2);
    // out = Lhat(v2) + y'0 - y'2 + b2
    prop2_kernel<48><<<pgrid, 256, 0, stream>>>(v2, 48, 1.f, Y2, 1.f,
                                                Y2 + 96, -1.f, 192, b2, 0, 40, 40,
                                                diag, row_start, csr_src, csr_w, out);
}